// Round 1
// baseline (541.144 us; speedup 1.0000x reference)
//
#include <hip/hip_runtime.h>
#include <math.h>

#define N_LBL 128
#define TS 128
#define BK 16

constexpr float T_INV = 2.0f;   // 1/T, T=0.5
constexpr float EPSf  = 1e-8f;

__device__ inline float wave_reduce_sum64(float v) {
#pragma unroll
  for (int m = 32; m >= 1; m >>= 1) v += __shfl_xor(v, m, 64);
  return v;
}

// zero D, counts, cursors, accum
__global__ void k_init(float* D, int* counts, int* cursors, float* accum, int n) {
  int i = blockIdx.x * blockDim.x + threadIdx.x;
  if (i < n) D[i] = 0.f;
  if (i < N_LBL) { counts[i] = 0; cursors[i] = 0; }
  if (i == 0) *accum = 0.f;
}

// per-row inverse norm + label histogram
__global__ __launch_bounds__(256) void k_row_norm(const float* __restrict__ x,
    const int* __restrict__ y, float* __restrict__ invn, int* __restrict__ counts,
    int n, int d) {
  int row = blockIdx.x;
  int t = threadIdx.x;
  const float4* xr = (const float4*)(x + (size_t)row * d);
  float ss = 0.f;
  for (int i = t; i < d / 4; i += 256) {
    float4 v = xr[i];
    ss += v.x * v.x + v.y * v.y + v.z * v.z + v.w * v.w;
  }
  __shared__ float part[4];
  ss = wave_reduce_sum64(ss);
  int lane = t & 63, wid = t >> 6;
  if (lane == 0) part[wid] = ss;
  __syncthreads();
  if (t == 0) {
    float tot = part[0] + part[1] + part[2] + part[3];
    float nrm = fmaxf(sqrtf(tot), EPSf);
    invn[row] = 1.0f / nrm;
    atomicAdd(&counts[y[row]], 1);
  }
}

__global__ void k_scan(const int* __restrict__ counts, int* __restrict__ offs) {
  if (threadIdx.x == 0 && blockIdx.x == 0) {
    int acc = 0;
    for (int l = 0; l < N_LBL; ++l) { offs[l] = acc; acc += counts[l]; }
    offs[N_LBL] = acc;
  }
}

__global__ void k_scatter(const int* __restrict__ y, const int* __restrict__ offs,
    int* __restrict__ cursors, int* __restrict__ rows, int n) {
  int i = blockIdx.x * blockDim.x + threadIdx.x;
  if (i < n) {
    int l = y[i];
    int pos = atomicAdd(&cursors[l], 1);
    rows[offs[l] + pos] = i;
  }
}

// Pass A: full Gram, accumulate diff-label exp-sums into D[row]
__global__ __launch_bounds__(256) void k_gram(const float* __restrict__ x,
    const float* __restrict__ invn, const int* __restrict__ y,
    float* __restrict__ D, int n, int d) {
  __shared__ float As[BK][TS + 4];
  __shared__ float Bs[BK][TS + 4];
  __shared__ int   yr[TS];  __shared__ int   yc[TS];
  __shared__ float ir[TS];  __shared__ float ic[TS];

  int nb = n / TS;
  int by = blockIdx.x / nb, bx = blockIdx.x % nb;
  int rowBase = by * TS, colBase = bx * TS;
  int t = threadIdx.x, tx = t & 15, ty = t >> 4;

  if (t < TS) {
    yr[t] = y[rowBase + t]; yc[t] = y[colBase + t];
    ir[t] = invn[rowBase + t]; ic[t] = invn[colBase + t];
  }

  float c[8][8] = {};
  for (int k0 = 0; k0 < d; k0 += BK) {
    __syncthreads();
#pragma unroll
    for (int i = 0; i < 8; ++i) {
      int e = t + i * 256;
      int k = e & 15, m = e >> 4;
      As[k][m] = x[(size_t)(rowBase + m) * d + k0 + k];
      Bs[k][m] = x[(size_t)(colBase + m) * d + k0 + k];
    }
    __syncthreads();
#pragma unroll
    for (int k = 0; k < BK; ++k) {
      float a[8], b[8];
      float4 a0 = *(const float4*)&As[k][ty * 8];
      float4 a1 = *(const float4*)&As[k][ty * 8 + 4];
      float4 b0 = *(const float4*)&Bs[k][tx * 8];
      float4 b1 = *(const float4*)&Bs[k][tx * 8 + 4];
      a[0]=a0.x; a[1]=a0.y; a[2]=a0.z; a[3]=a0.w; a[4]=a1.x; a[5]=a1.y; a[6]=a1.z; a[7]=a1.w;
      b[0]=b0.x; b[1]=b0.y; b[2]=b0.z; b[3]=b0.w; b[4]=b1.x; b[5]=b1.y; b[6]=b1.z; b[7]=b1.w;
#pragma unroll
      for (int i = 0; i < 8; ++i)
#pragma unroll
        for (int j = 0; j < 8; ++j)
          c[i][j] = fmaf(a[i], b[j], c[i][j]);
    }
  }

  // epilogue: clip, exp, diff-label row sums
#pragma unroll
  for (int i = 0; i < 8; ++i) {
    int lr = ty * 8 + i;
    int yi = yr[lr];
    float ivr = ir[lr];
    float rs = 0.f;
#pragma unroll
    for (int j = 0; j < 8; ++j) {
      int lc = tx * 8 + j;
      float sim = c[i][j] * ivr * ic[lc];
      sim = fminf(fmaxf(sim, -1.0f + EPSf), 1.0f - EPSf);
      float s = fminf(expf(sim * T_INV), 1e10f);
      if (yc[lc] != yi) rs += s;
    }
    // reduce across the 16 threads sharing this row (tx = bits 0-3 of lane)
#pragma unroll
    for (int m = 8; m >= 1; m >>= 1) rs += __shfl_xor(rs, m, 16);
    if (tx == 0) atomicAdd(&D[rowBase + lr], rs);
  }
}

// Pass B: same-label pairs -> loss terms
__global__ __launch_bounds__(256) void k_loss(const float* __restrict__ x,
    const float* __restrict__ invn, const int* __restrict__ y,
    const int* __restrict__ offs, const int* __restrict__ rows,
    const float* __restrict__ D, float* __restrict__ accum, int n, int d) {
  int i = blockIdx.x;
  int t = threadIdx.x, lane = t & 63, wid = t >> 6;
  __shared__ float4 xi4[256];   // d <= 1024
  __shared__ float wpart[4];

  const float4* xr = (const float4*)(x + (size_t)i * d);
  for (int q = t; q < d / 4; q += 256) xi4[q] = xr[q];
  __syncthreads();

  int g = y[i];
  int start = offs[g], end = offs[g + 1];
  float invi = invn[i];
  float Di = D[i];
  float wsum = 0.f;

  for (int idx = start + wid; idx < end; idx += 4) {
    int j = rows[idx];
    if (j == i) continue;
    const float4* xj = (const float4*)(x + (size_t)j * d);
    float acc = 0.f;
#pragma unroll 4
    for (int q = 0; q < d / 256; ++q) {
      float4 vj = xj[lane + 64 * q];
      float4 vi = xi4[lane + 64 * q];
      acc = fmaf(vj.x, vi.x, acc);
      acc = fmaf(vj.y, vi.y, acc);
      acc = fmaf(vj.z, vi.z, acc);
      acc = fmaf(vj.w, vi.w, acc);
    }
    acc = wave_reduce_sum64(acc);
    if (lane == 0) {
      float sim = acc * invi * invn[j];
      sim = fminf(fmaxf(sim, -1.0f + EPSf), 1.0f - EPSf);
      float s = fminf(expf(sim * T_INV), 1e10f);
      wsum += logf(s + Di + EPSf) - logf(s);
    }
  }

  if (lane == 0) wpart[wid] = wsum;
  __syncthreads();
  if (t == 0) atomicAdd(accum, wpart[0] + wpart[1] + wpart[2] + wpart[3]);
}

__global__ void k_final(const float* __restrict__ accum, float* __restrict__ out,
    int out_size, int n) {
  int i = blockIdx.x * blockDim.x + threadIdx.x;
  if (i < out_size) out[i] = *accum / (2.0f * n);
}

extern "C" void kernel_launch(void* const* d_in, const int* in_sizes, int n_in,
                              void* d_out, int out_size, void* d_ws, size_t ws_size,
                              hipStream_t stream) {
  const float* x = (const float*)d_in[0];
  const int*   y = (const int*)d_in[1];
  int n = in_sizes[1];
  int d = in_sizes[0] / n;

  char* ws = (char*)d_ws;
  float* invn    = (float*)(ws);                 // n floats (<=16KB)
  float* D       = (float*)(ws + 16384);         // n floats
  int*   counts  = (int*)(ws + 32768);           // 128
  int*   cursors = (int*)(ws + 32768 + 512);     // 128
  int*   offs    = (int*)(ws + 32768 + 1024);    // 129
  int*   rows    = (int*)(ws + 32768 + 2048);    // n ints
  float* accum   = (float*)(ws + 32768 + 2048 + 16384);

  k_init<<<(n + 255) / 256, 256, 0, stream>>>(D, counts, cursors, accum, n);
  k_row_norm<<<n, 256, 0, stream>>>(x, y, invn, counts, n, d);
  k_scan<<<1, 64, 0, stream>>>(counts, offs);
  k_scatter<<<(n + 255) / 256, 256, 0, stream>>>(y, offs, cursors, rows, n);

  int nb = n / TS;
  k_gram<<<nb * nb, 256, 0, stream>>>(x, invn, y, D, n, d);
  k_loss<<<n, 256, 0, stream>>>(x, invn, y, offs, rows, D, accum, n, d);
  k_final<<<1, 64, 0, stream>>>(accum, (float*)d_out, out_size, n);
}

// Round 2
// 181.080 us; speedup vs baseline: 2.9884x; 2.9884x over previous
//
#include <hip/hip_runtime.h>
#include <math.h>

typedef float f32x4 __attribute__((ext_vector_type(4)));
typedef short bf16x8 __attribute__((ext_vector_type(8)));

#define N_LBL 128
#define TS 128

constexpr float T_INV = 2.0f;   // 1/T, T=0.5
constexpr float EPSf  = 1e-8f;

__device__ inline float wave_reduce_sum64(float v) {
#pragma unroll
  for (int m = 32; m >= 1; m >>= 1) v += __shfl_xor(v, m, 64);
  return v;
}

__device__ inline unsigned short f2bf(float f) {  // RNE
  unsigned int u = __float_as_uint(f);
  unsigned int r = (u + 0x7FFFu + ((u >> 16) & 1u)) >> 16;
  return (unsigned short)r;
}

__global__ void k_init(float* D, int* counts, int* cursors, float* accum, int n) {
  int i = blockIdx.x * blockDim.x + threadIdx.x;
  if (i < n) D[i] = 0.f;
  if (i < N_LBL) { counts[i] = 0; cursors[i] = 0; }
  if (i == 0) *accum = 0.f;
}

__global__ __launch_bounds__(256) void k_row_norm(const float* __restrict__ x,
    const int* __restrict__ y, float* __restrict__ invn, int* __restrict__ counts,
    int n, int d) {
  int row = blockIdx.x;
  int t = threadIdx.x;
  const float4* xr = (const float4*)(x + (size_t)row * d);
  float ss = 0.f;
  for (int i = t; i < d / 4; i += 256) {
    float4 v = xr[i];
    ss += v.x * v.x + v.y * v.y + v.z * v.z + v.w * v.w;
  }
  __shared__ float part[4];
  ss = wave_reduce_sum64(ss);
  int lane = t & 63, wid = t >> 6;
  if (lane == 0) part[wid] = ss;
  __syncthreads();
  if (t == 0) {
    float tot = part[0] + part[1] + part[2] + part[3];
    float nrm = fmaxf(sqrtf(tot), EPSf);
    invn[row] = 1.0f / nrm;
    atomicAdd(&counts[y[row]], 1);
  }
}

__global__ void k_scan(const int* __restrict__ counts, int* __restrict__ offs) {
  if (threadIdx.x == 0 && blockIdx.x == 0) {
    int acc = 0;
    for (int l = 0; l < N_LBL; ++l) { offs[l] = acc; acc += counts[l]; }
    offs[N_LBL] = acc;
  }
}

__global__ void k_scatter(const int* __restrict__ y, const int* __restrict__ offs,
    int* __restrict__ cursors, int* __restrict__ rows, int n) {
  int i = blockIdx.x * blockDim.x + threadIdx.x;
  if (i < n) {
    int l = y[i];
    int pos = atomicAdd(&cursors[l], 1);
    rows[offs[l] + pos] = i;
  }
}

// Pass A: upper-triangular blocked Gram via bf16 MFMA.
// Off-diagonal blocks scatter row sums AND col sums (symmetry); diagonal
// blocks compute the full tile and scatter row sums only.
__global__ __launch_bounds__(256) void k_gram_mfma(const float* __restrict__ x,
    const float* __restrict__ invn, const int* __restrict__ y,
    float* __restrict__ D, int n, int d, int nb) {
  // triangular decode: bid -> (by, bx) with by <= bx
  int bid = blockIdx.x;
  int by = 0, rowlen = nb, rem = bid;
  while (rem >= rowlen) { rem -= rowlen; ++by; --rowlen; }
  int bx = by + rem;
  int rowBase = by * TS, colBase = bx * TS;
  bool diag = (bx == by);

  __shared__ char ldsA[128 * 128];   // 128 rows x 64 bf16 (128 B/row), XOR-swizzled
  __shared__ char ldsB[128 * 128];
  __shared__ float ir_s[128], ic_s[128];
  __shared__ int yr_s[128], yc_s[128];

  int t = threadIdx.x;
  int lane = t & 63, wid = t >> 6;
  int wr = wid >> 1, wc = wid & 1;          // 2x2 wave grid, 64x64 per wave
  int l15 = lane & 15, l4 = lane >> 4;

  if (t < 128) {
    ir_s[t] = invn[rowBase + t]; yr_s[t] = y[rowBase + t];
    ic_s[t] = invn[colBase + t]; yc_s[t] = y[colBase + t];
  }

  f32x4 acc[4][4];
#pragma unroll
  for (int m = 0; m < 4; ++m)
#pragma unroll
    for (int nn = 0; nn < 4; ++nn) acc[m][nn] = (f32x4){0.f, 0.f, 0.f, 0.f};

  const char* ldsBr = diag ? ldsA : ldsB;

  for (int k0 = 0; k0 < d; k0 += 64) {
    __syncthreads();
    // stage A: 128 rows x 64 floats -> bf16, swizzled. chunk c: row=c>>4, fc=c&15
#pragma unroll
    for (int i = 0; i < 8; ++i) {
      int c = t + i * 256;
      int row = c >> 4, fc = c & 15;
      float4 v = *(const float4*)(x + (size_t)(rowBase + row) * d + k0 + fc * 4);
      ushort4 h;
      h.x = f2bf(v.x); h.y = f2bf(v.y); h.z = f2bf(v.z); h.w = f2bf(v.w);
      int off = row * 128 + ((((fc >> 1) ^ (row & 7))) << 4) + (fc & 1) * 8;
      *(ushort4*)(ldsA + off) = h;
    }
    if (!diag) {
#pragma unroll
      for (int i = 0; i < 8; ++i) {
        int c = t + i * 256;
        int row = c >> 4, fc = c & 15;
        float4 v = *(const float4*)(x + (size_t)(colBase + row) * d + k0 + fc * 4);
        ushort4 h;
        h.x = f2bf(v.x); h.y = f2bf(v.y); h.z = f2bf(v.z); h.w = f2bf(v.w);
        int off = row * 128 + ((((fc >> 1) ^ (row & 7))) << 4) + (fc & 1) * 8;
        *(ushort4*)(ldsB + off) = h;
      }
    }
    __syncthreads();

#pragma unroll
    for (int kk = 0; kk < 2; ++kk) {
      bf16x8 a[4], b[4];
#pragma unroll
      for (int m = 0; m < 4; ++m) {
        int row = wr * 64 + m * 16 + l15;
        int slot = (kk * 4 + l4) ^ (row & 7);
        a[m] = *(const bf16x8*)(ldsA + row * 128 + slot * 16);
      }
#pragma unroll
      for (int nn = 0; nn < 4; ++nn) {
        int row = wc * 64 + nn * 16 + l15;
        int slot = (kk * 4 + l4) ^ (row & 7);
        b[nn] = *(const bf16x8*)(ldsBr + row * 128 + slot * 16);
      }
#pragma unroll
      for (int m = 0; m < 4; ++m)
#pragma unroll
        for (int nn = 0; nn < 4; ++nn)
          acc[m][nn] = __builtin_amdgcn_mfma_f32_16x16x32_bf16(a[m], b[nn], acc[m][nn], 0, 0, 0);
    }
  }

  // epilogue: C/D frag layout col=lane&15, row=(lane>>4)*4+r
  float cs[4] = {0.f, 0.f, 0.f, 0.f};
#pragma unroll
  for (int m = 0; m < 4; ++m) {
#pragma unroll
    for (int r = 0; r < 4; ++r) {
      int lr = wr * 64 + m * 16 + l4 * 4 + r;
      float ivr = ir_s[lr];
      int yi = yr_s[lr];
      float rs = 0.f;
#pragma unroll
      for (int nn = 0; nn < 4; ++nn) {
        int lc = wc * 64 + nn * 16 + l15;
        float sim = acc[m][nn][r] * ivr * ic_s[lc];
        sim = fminf(fmaxf(sim, -1.0f + EPSf), 1.0f - EPSf);
        float s = fminf(__expf(sim * T_INV), 1e10f);
        if (yc_s[lc] != yi) { rs += s; cs[nn] += s; }
      }
      rs += __shfl_xor(rs, 1, 64);
      rs += __shfl_xor(rs, 2, 64);
      rs += __shfl_xor(rs, 4, 64);
      rs += __shfl_xor(rs, 8, 64);
      if (l15 == 0) atomicAdd(&D[rowBase + lr], rs);
    }
  }
  if (!diag) {
#pragma unroll
    for (int nn = 0; nn < 4; ++nn) {
      float v = cs[nn];
      v += __shfl_xor(v, 16, 64);
      v += __shfl_xor(v, 32, 64);
      if (l4 == 0) atomicAdd(&D[colBase + wc * 64 + nn * 16 + l15], v);
    }
  }
}

// Pass B: same-label pairs -> loss terms
__global__ __launch_bounds__(256) void k_loss(const float* __restrict__ x,
    const float* __restrict__ invn, const int* __restrict__ y,
    const int* __restrict__ offs, const int* __restrict__ rows,
    const float* __restrict__ D, float* __restrict__ accum, int n, int d) {
  int i = blockIdx.x;
  int t = threadIdx.x, lane = t & 63, wid = t >> 6;
  __shared__ float4 xi4[256];   // d <= 1024
  __shared__ float wpart[4];

  const float4* xr = (const float4*)(x + (size_t)i * d);
  for (int q = t; q < d / 4; q += 256) xi4[q] = xr[q];
  __syncthreads();

  int g = y[i];
  int start = offs[g], end = offs[g + 1];
  float invi = invn[i];
  float Di = D[i];
  float wsum = 0.f;

  for (int idx = start + wid; idx < end; idx += 4) {
    int j = rows[idx];
    if (j == i) continue;
    const float4* xj = (const float4*)(x + (size_t)j * d);
    float acc = 0.f;
#pragma unroll 4
    for (int q = 0; q < d / 256; ++q) {
      float4 vj = xj[lane + 64 * q];
      float4 vi = xi4[lane + 64 * q];
      acc = fmaf(vj.x, vi.x, acc);
      acc = fmaf(vj.y, vi.y, acc);
      acc = fmaf(vj.z, vi.z, acc);
      acc = fmaf(vj.w, vi.w, acc);
    }
    acc = wave_reduce_sum64(acc);
    if (lane == 0) {
      float sim = acc * invi * invn[j];
      sim = fminf(fmaxf(sim, -1.0f + EPSf), 1.0f - EPSf);
      float s = fminf(expf(sim * T_INV), 1e10f);
      wsum += logf(s + Di + EPSf) - logf(s);
    }
  }

  if (lane == 0) wpart[wid] = wsum;
  __syncthreads();
  if (t == 0) atomicAdd(accum, wpart[0] + wpart[1] + wpart[2] + wpart[3]);
}

__global__ void k_final(const float* __restrict__ accum, float* __restrict__ out,
    int out_size, int n) {
  int i = blockIdx.x * blockDim.x + threadIdx.x;
  if (i < out_size) out[i] = *accum / (2.0f * n);
}

extern "C" void kernel_launch(void* const* d_in, const int* in_sizes, int n_in,
                              void* d_out, int out_size, void* d_ws, size_t ws_size,
                              hipStream_t stream) {
  const float* x = (const float*)d_in[0];
  const int*   y = (const int*)d_in[1];
  int n = in_sizes[1];
  int d = in_sizes[0] / n;

  char* ws = (char*)d_ws;
  float* invn    = (float*)(ws);                 // n floats (<=16KB)
  float* D       = (float*)(ws + 16384);         // n floats
  int*   counts  = (int*)(ws + 32768);           // 128
  int*   cursors = (int*)(ws + 32768 + 512);     // 128
  int*   offs    = (int*)(ws + 32768 + 1024);    // 129
  int*   rows    = (int*)(ws + 32768 + 2048);    // n ints
  float* accum   = (float*)(ws + 32768 + 2048 + 16384);

  k_init<<<(n + 255) / 256, 256, 0, stream>>>(D, counts, cursors, accum, n);
  k_row_norm<<<n, 256, 0, stream>>>(x, y, invn, counts, n, d);
  k_scan<<<1, 64, 0, stream>>>(counts, offs);
  k_scatter<<<(n + 255) / 256, 256, 0, stream>>>(y, offs, cursors, rows, n);

  int nb = n / TS;
  int nblocks = nb * (nb + 1) / 2;
  k_gram_mfma<<<nblocks, 256, 0, stream>>>(x, invn, y, D, n, d, nb);
  k_loss<<<n, 256, 0, stream>>>(x, invn, y, offs, rows, D, accum, n, d);
  k_final<<<1, 64, 0, stream>>>(accum, (float*)d_out, out_size, n);
}

// Round 3
// 139.023 us; speedup vs baseline: 3.8925x; 1.3025x over previous
//
#include <hip/hip_runtime.h>
#include <math.h>

typedef float f32x4 __attribute__((ext_vector_type(4)));
typedef short bf16x8 __attribute__((ext_vector_type(8)));

#define N_LBL 128
#define TS 128
#define MAXG 128

constexpr float T_INV = 2.0f;   // 1/T, T=0.5
constexpr float EPSf  = 1e-8f;

__device__ inline float wave_reduce_sum64(float v) {
#pragma unroll
  for (int m = 32; m >= 1; m >>= 1) v += __shfl_xor(v, m, 64);
  return v;
}

__device__ inline unsigned short f2bf(float f) {  // RNE
  unsigned int u = __float_as_uint(f);
  unsigned int r = (u + 0x7FFFu + ((u >> 16) & 1u)) >> 16;
  return (unsigned short)r;
}

__global__ void k_init(float* D, int* counts, int* cursors, float* accum, int n) {
  int i = blockIdx.x * blockDim.x + threadIdx.x;
  if (i < n) D[i] = 0.f;
  if (i < N_LBL) { counts[i] = 0; cursors[i] = 0; }
  if (i == 0) *accum = 0.f;
}

__global__ __launch_bounds__(256) void k_row_norm(const float* __restrict__ x,
    const int* __restrict__ y, float* __restrict__ invn, int* __restrict__ counts,
    int n, int d) {
  int row = blockIdx.x;
  int t = threadIdx.x;
  const float4* xr = (const float4*)(x + (size_t)row * d);
  float ss = 0.f;
  for (int i = t; i < d / 4; i += 256) {
    float4 v = xr[i];
    ss += v.x * v.x + v.y * v.y + v.z * v.z + v.w * v.w;
  }
  __shared__ float part[4];
  ss = wave_reduce_sum64(ss);
  int lane = t & 63, wid = t >> 6;
  if (lane == 0) part[wid] = ss;
  __syncthreads();
  if (t == 0) {
    float tot = part[0] + part[1] + part[2] + part[3];
    float nrm = fmaxf(sqrtf(tot), EPSf);
    invn[row] = 1.0f / nrm;
    atomicAdd(&counts[y[row]], 1);
  }
}

__global__ void k_scan(const int* __restrict__ counts, int* __restrict__ offs) {
  if (threadIdx.x == 0 && blockIdx.x == 0) {
    int acc = 0;
    for (int l = 0; l < N_LBL; ++l) { offs[l] = acc; acc += counts[l]; }
    offs[N_LBL] = acc;
  }
}

__global__ void k_scatter(const int* __restrict__ y, const int* __restrict__ offs,
    int* __restrict__ cursors, int* __restrict__ rows, int* __restrict__ rank, int n) {
  int i = blockIdx.x * blockDim.x + threadIdx.x;
  if (i < n) {
    int l = y[i];
    int pos = atomicAdd(&cursors[l], 1);
    rows[offs[l] + pos] = i;
    rank[i] = pos;
  }
}

// Pass A: upper-triangular blocked Gram via bf16 MFMA.
// Off-diagonal blocks scatter row sums AND col sums (symmetry); diagonal
// blocks compute the full tile and scatter row sums only. Same-label s_ij
// values are persisted to S[i*MAXG + rank[j]] for pass B.
__global__ __launch_bounds__(256) void k_gram_mfma(const float* __restrict__ x,
    const float* __restrict__ invn, const int* __restrict__ y,
    const int* __restrict__ rank, float* __restrict__ D, float* __restrict__ S,
    int n, int d, int nb) {
  // triangular decode: bid -> (by, bx) with by <= bx
  int bid = blockIdx.x;
  int by = 0, rowlen = nb, rem = bid;
  while (rem >= rowlen) { rem -= rowlen; ++by; --rowlen; }
  int bx = by + rem;
  int rowBase = by * TS, colBase = bx * TS;
  bool diag = (bx == by);

  __shared__ char ldsA[128 * 128];   // 128 rows x 64 bf16 (128 B/row), XOR-swizzled
  __shared__ char ldsB[128 * 128];
  __shared__ float ir_s[128], ic_s[128];
  __shared__ int yr_s[128], yc_s[128];
  __shared__ int rr_s[128], rc_s[128];

  int t = threadIdx.x;
  int lane = t & 63, wid = t >> 6;
  int wr = wid >> 1, wc = wid & 1;          // 2x2 wave grid, 64x64 per wave
  int l15 = lane & 15, l4 = lane >> 4;

  if (t < 128) {
    ir_s[t] = invn[rowBase + t]; yr_s[t] = y[rowBase + t]; rr_s[t] = rank[rowBase + t];
    ic_s[t] = invn[colBase + t]; yc_s[t] = y[colBase + t]; rc_s[t] = rank[colBase + t];
  }

  f32x4 acc[4][4];
#pragma unroll
  for (int m = 0; m < 4; ++m)
#pragma unroll
    for (int nn = 0; nn < 4; ++nn) acc[m][nn] = (f32x4){0.f, 0.f, 0.f, 0.f};

  const char* ldsBr = diag ? ldsA : ldsB;

  for (int k0 = 0; k0 < d; k0 += 64) {
    __syncthreads();
    // stage A: 128 rows x 64 floats -> bf16, swizzled. chunk c: row=c>>4, fc=c&15
#pragma unroll
    for (int i = 0; i < 8; ++i) {
      int c = t + i * 256;
      int row = c >> 4, fc = c & 15;
      float4 v = *(const float4*)(x + (size_t)(rowBase + row) * d + k0 + fc * 4);
      ushort4 h;
      h.x = f2bf(v.x); h.y = f2bf(v.y); h.z = f2bf(v.z); h.w = f2bf(v.w);
      int off = row * 128 + ((((fc >> 1) ^ (row & 7))) << 4) + (fc & 1) * 8;
      *(ushort4*)(ldsA + off) = h;
    }
    if (!diag) {
#pragma unroll
      for (int i = 0; i < 8; ++i) {
        int c = t + i * 256;
        int row = c >> 4, fc = c & 15;
        float4 v = *(const float4*)(x + (size_t)(colBase + row) * d + k0 + fc * 4);
        ushort4 h;
        h.x = f2bf(v.x); h.y = f2bf(v.y); h.z = f2bf(v.z); h.w = f2bf(v.w);
        int off = row * 128 + ((((fc >> 1) ^ (row & 7))) << 4) + (fc & 1) * 8;
        *(ushort4*)(ldsB + off) = h;
      }
    }
    __syncthreads();

#pragma unroll
    for (int kk = 0; kk < 2; ++kk) {
      bf16x8 a[4], b[4];
#pragma unroll
      for (int m = 0; m < 4; ++m) {
        int row = wr * 64 + m * 16 + l15;
        int slot = (kk * 4 + l4) ^ (row & 7);
        a[m] = *(const bf16x8*)(ldsA + row * 128 + slot * 16);
      }
#pragma unroll
      for (int nn = 0; nn < 4; ++nn) {
        int row = wc * 64 + nn * 16 + l15;
        int slot = (kk * 4 + l4) ^ (row & 7);
        b[nn] = *(const bf16x8*)(ldsBr + row * 128 + slot * 16);
      }
#pragma unroll
      for (int m = 0; m < 4; ++m)
#pragma unroll
        for (int nn = 0; nn < 4; ++nn)
          acc[m][nn] = __builtin_amdgcn_mfma_f32_16x16x32_bf16(a[m], b[nn], acc[m][nn], 0, 0, 0);
    }
  }

  // epilogue: C/D frag layout col=lane&15, row=(lane>>4)*4+r
  float cs[4] = {0.f, 0.f, 0.f, 0.f};
#pragma unroll
  for (int m = 0; m < 4; ++m) {
#pragma unroll
    for (int r = 0; r < 4; ++r) {
      int lr = wr * 64 + m * 16 + l4 * 4 + r;
      int gi = rowBase + lr;
      float ivr = ir_s[lr];
      int yi = yr_s[lr];
      float rs = 0.f;
#pragma unroll
      for (int nn = 0; nn < 4; ++nn) {
        int lc = wc * 64 + nn * 16 + l15;
        int gj = colBase + lc;
        float sim = acc[m][nn][r] * ivr * ic_s[lc];
        sim = fminf(fmaxf(sim, -1.0f + EPSf), 1.0f - EPSf);
        float s = fminf(__expf(sim * T_INV), 1e10f);
        if (yc_s[lc] != yi) {
          rs += s; cs[nn] += s;
        } else if (S && gi != gj) {
          S[(size_t)gi * MAXG + rc_s[lc]] = s;
          if (!diag) S[(size_t)gj * MAXG + rr_s[lr]] = s;
        }
      }
      rs += __shfl_xor(rs, 1, 64);
      rs += __shfl_xor(rs, 2, 64);
      rs += __shfl_xor(rs, 4, 64);
      rs += __shfl_xor(rs, 8, 64);
      if (l15 == 0) atomicAdd(&D[rowBase + lr], rs);
    }
  }
  if (!diag) {
#pragma unroll
    for (int nn = 0; nn < 4; ++nn) {
      float v = cs[nn];
      v += __shfl_xor(v, 16, 64);
      v += __shfl_xor(v, 32, 64);
      if (l4 == 0) atomicAdd(&D[colBase + wc * 64 + nn * 16 + l15], v);
    }
  }
}

// Pass B (fast): read persisted same-label s values, sum the loss terms.
__global__ __launch_bounds__(256) void k_loss2(const int* __restrict__ y,
    const int* __restrict__ offs, const int* __restrict__ rows,
    const float* __restrict__ D, const float* __restrict__ S,
    float* __restrict__ accum, int n) {
  int gid = blockIdx.x * blockDim.x + threadIdx.x;
  int i = gid >> 7;          // MAXG = 128
  int slot = gid & (MAXG - 1);
  float term = 0.f;
  if (i < n) {
    int g = y[i];
    int start = offs[g], cnt = offs[g + 1] - start;
    if (slot < cnt) {
      int j = rows[start + slot];
      if (j != i) {
        float s = S[(size_t)i * MAXG + slot];
        term = logf(s + D[i] + EPSf) - logf(s);
      }
    }
  }
  term = wave_reduce_sum64(term);
  __shared__ float part[4];
  int lane = threadIdx.x & 63, wid = threadIdx.x >> 6;
  if (lane == 0) part[wid] = term;
  __syncthreads();
  if (threadIdx.x == 0) atomicAdd(accum, part[0] + part[1] + part[2] + part[3]);
}

// Pass B (fallback, ws too small): recompute dots for same-label pairs
__global__ __launch_bounds__(256) void k_loss(const float* __restrict__ x,
    const float* __restrict__ invn, const int* __restrict__ y,
    const int* __restrict__ offs, const int* __restrict__ rows,
    const float* __restrict__ D, float* __restrict__ accum, int n, int d) {
  int i = blockIdx.x;
  int t = threadIdx.x, lane = t & 63, wid = t >> 6;
  __shared__ float4 xi4[256];
  __shared__ float wpart[4];

  const float4* xr = (const float4*)(x + (size_t)i * d);
  for (int q = t; q < d / 4; q += 256) xi4[q] = xr[q];
  __syncthreads();

  int g = y[i];
  int start = offs[g], end = offs[g + 1];
  float invi = invn[i];
  float Di = D[i];
  float wsum = 0.f;

  for (int idx = start + wid; idx < end; idx += 4) {
    int j = rows[idx];
    if (j == i) continue;
    const float4* xj = (const float4*)(x + (size_t)j * d);
    float acc = 0.f;
#pragma unroll 4
    for (int q = 0; q < d / 256; ++q) {
      float4 vj = xj[lane + 64 * q];
      float4 vi = xi4[lane + 64 * q];
      acc = fmaf(vj.x, vi.x, acc);
      acc = fmaf(vj.y, vi.y, acc);
      acc = fmaf(vj.z, vi.z, acc);
      acc = fmaf(vj.w, vi.w, acc);
    }
    acc = wave_reduce_sum64(acc);
    if (lane == 0) {
      float sim = acc * invi * invn[j];
      sim = fminf(fmaxf(sim, -1.0f + EPSf), 1.0f - EPSf);
      float s = fminf(expf(sim * T_INV), 1e10f);
      wsum += logf(s + Di + EPSf) - logf(s);
    }
  }

  if (lane == 0) wpart[wid] = wsum;
  __syncthreads();
  if (t == 0) atomicAdd(accum, wpart[0] + wpart[1] + wpart[2] + wpart[3]);
}

__global__ void k_final(const float* __restrict__ accum, float* __restrict__ out,
    int out_size, int n) {
  int i = blockIdx.x * blockDim.x + threadIdx.x;
  if (i < out_size) out[i] = *accum / (2.0f * n);
}

extern "C" void kernel_launch(void* const* d_in, const int* in_sizes, int n_in,
                              void* d_out, int out_size, void* d_ws, size_t ws_size,
                              hipStream_t stream) {
  const float* x = (const float*)d_in[0];
  const int*   y = (const int*)d_in[1];
  int n = in_sizes[1];
  int d = in_sizes[0] / n;

  char* ws = (char*)d_ws;
  float* invn    = (float*)(ws);                 // n floats (<=16KB)
  float* D       = (float*)(ws + 16384);         // n floats
  int*   counts  = (int*)(ws + 32768);           // 128
  int*   cursors = (int*)(ws + 32768 + 512);     // 128
  int*   offs    = (int*)(ws + 32768 + 1024);    // 129
  int*   rows    = (int*)(ws + 32768 + 2048);    // n ints
  int*   rank    = (int*)(ws + 32768 + 2048 + 16384);   // n ints
  float* accum   = (float*)(ws + 32768 + 2048 + 32768);
  float* S       = (float*)(ws + 32768 + 2048 + 32768 + 256);

  size_t need = (size_t)(32768 + 2048 + 32768 + 256) + (size_t)n * MAXG * 4;
  bool fast = ws_size >= need;

  k_init<<<(n + 255) / 256, 256, 0, stream>>>(D, counts, cursors, accum, n);
  k_row_norm<<<n, 256, 0, stream>>>(x, y, invn, counts, n, d);
  k_scan<<<1, 64, 0, stream>>>(counts, offs);
  k_scatter<<<(n + 255) / 256, 256, 0, stream>>>(y, offs, cursors, rows, rank, n);

  int nb = n / TS;
  int nblocks = nb * (nb + 1) / 2;
  k_gram_mfma<<<nblocks, 256, 0, stream>>>(x, invn, y, rank, D, fast ? S : nullptr, n, d, nb);
  if (fast) {
    k_loss2<<<(n * MAXG + 255) / 256, 256, 0, stream>>>(y, offs, rows, D, S, accum, n);
  } else {
    k_loss<<<n, 256, 0, stream>>>(x, invn, y, offs, rows, D, accum, n, d);
  }
  k_final<<<1, 64, 0, stream>>>(accum, (float*)d_out, out_size, n);
}

// Round 4
// 85.910 us; speedup vs baseline: 6.2989x; 1.6182x over previous
//
#include <hip/hip_runtime.h>
#include <math.h>

typedef float f32x4 __attribute__((ext_vector_type(4)));
typedef short bf16x8 __attribute__((ext_vector_type(8)));

#define N_LBL 128
#define TS 128
#define MAXG 128

constexpr float T_INV = 2.0f;   // 1/T, T=0.5
constexpr float EPSf  = 1e-8f;

__device__ inline float wave_reduce_sum64(float v) {
#pragma unroll
  for (int m = 32; m >= 1; m >>= 1) v += __shfl_xor(v, m, 64);
  return v;
}

__device__ inline unsigned short f2bf(float f) {  // RNE
  unsigned int u = __float_as_uint(f);
  unsigned int r = (u + 0x7FFFu + ((u >> 16) & 1u)) >> 16;
  return (unsigned short)r;
}

// Fused: row inverse-norms, D zero, accum zero, x -> bf16 copy (if xb).
__global__ __launch_bounds__(256) void k_prep(const float* __restrict__ x,
    float* __restrict__ invn, float* __restrict__ D,
    unsigned short* __restrict__ xb, float* __restrict__ accum, int n, int d) {
  int row = blockIdx.x;
  int t = threadIdx.x;
  const float4* xr = (const float4*)(x + (size_t)row * d);
  float ss = 0.f;
  for (int i = t; i < d / 4; i += 256) {
    float4 v = xr[i];
    ss += v.x * v.x + v.y * v.y + v.z * v.z + v.w * v.w;
    if (xb) {
      ushort4 h;
      h.x = f2bf(v.x); h.y = f2bf(v.y); h.z = f2bf(v.z); h.w = f2bf(v.w);
      *(ushort4*)(xb + (size_t)row * d + i * 4) = h;
    }
  }
  __shared__ float part[4];
  ss = wave_reduce_sum64(ss);
  int lane = t & 63, wid = t >> 6;
  if (lane == 0) part[wid] = ss;
  __syncthreads();
  if (t == 0) {
    float tot = part[0] + part[1] + part[2] + part[3];
    invn[row] = 1.0f / fmaxf(sqrtf(tot), EPSf);
    D[row] = 0.f;
    if (row == 0) *accum = 0.f;
  }
}

// Single-block label machinery: histogram -> scan -> scatter (LDS atomics).
__global__ __launch_bounds__(256) void k_labels(const int* __restrict__ y,
    int* __restrict__ offs_g, int* __restrict__ rows, int* __restrict__ rank, int n) {
  __shared__ int hist[N_LBL];
  __shared__ int curs[N_LBL];
  __shared__ int loffs[N_LBL + 1];
  int t = threadIdx.x;
  if (t < N_LBL) { hist[t] = 0; curs[t] = 0; }
  __syncthreads();
  for (int i = t; i < n; i += 256) atomicAdd(&hist[y[i]], 1);
  __syncthreads();
  if (t == 0) {
    int acc = 0;
    for (int l = 0; l < N_LBL; ++l) { loffs[l] = acc; acc += hist[l]; }
    loffs[N_LBL] = acc;
  }
  __syncthreads();
  if (t <= N_LBL) offs_g[t] = loffs[t];
  for (int i = t; i < n; i += 256) {
    int g = y[i];
    int pos = atomicAdd(&curs[g], 1);
    rows[loffs[g] + pos] = i;
    rank[i] = pos;
  }
}

// ---------------- Gram pass, fast path: global_load_lds from bf16 copy ----
// LDS panel: 128 rows x 64 bf16 (128 B/row); physical 16B chunk p of row r
// holds logical chunk p ^ (r&7)  (XOR swizzle applied on the per-lane
// GLOBAL source address; LDS dest is linear, as global_load_lds requires).
__global__ __launch_bounds__(256) void k_gram_ldsdma(
    const unsigned short* __restrict__ xb, const float* __restrict__ invn,
    const int* __restrict__ y, const int* __restrict__ rank,
    float* __restrict__ D, float* __restrict__ S, int n, int d, int nb) {
  int bid = blockIdx.x;
  int by = 0, rowlen = nb, rem = bid;
  while (rem >= rowlen) { rem -= rowlen; ++by; --rowlen; }
  int bx = by + rem;
  int rowBase = by * TS, colBase = bx * TS;
  bool diag = (bx == by);

  __shared__ char ldsA[128 * 128];
  __shared__ char ldsB[128 * 128];
  __shared__ float ir_s[128], ic_s[128];
  __shared__ int yr_s[128], yc_s[128];
  __shared__ int rr_s[128], rc_s[128];

  int t = threadIdx.x;
  int lane = t & 63, wid = t >> 6;
  int wr = wid >> 1, wc = wid & 1;          // 2x2 wave grid, 64x64 per wave
  int l15 = lane & 15, l4 = lane >> 4;

  if (t < 128) {
    ir_s[t] = invn[rowBase + t]; yr_s[t] = y[rowBase + t]; rr_s[t] = rank[rowBase + t];
    ic_s[t] = invn[colBase + t]; yc_s[t] = y[colBase + t]; rc_s[t] = rank[colBase + t];
  }

  f32x4 acc[4][4];
#pragma unroll
  for (int m = 0; m < 4; ++m)
#pragma unroll
    for (int nn = 0; nn < 4; ++nn) acc[m][nn] = (f32x4){0.f, 0.f, 0.f, 0.f};

  const char* ldsBr = diag ? ldsA : ldsB;
  int lrow = lane >> 3, lp = lane & 7;       // lane's row-in-segment / chunk

  for (int g = 0; g < d / 64; ++g) {
    __syncthreads();
#pragma unroll
    for (int j = 0; j < 4; ++j) {
      int seg = wid * 4 + j;                 // 0..15, 8 rows each
      int row = seg * 8 + lrow;
      const unsigned short* src = xb + (size_t)(rowBase + row) * d + g * 64
                                  + ((lp ^ (row & 7)) << 3);
      __builtin_amdgcn_global_load_lds(
          (const __attribute__((address_space(1))) void*)src,
          (__attribute__((address_space(3))) void*)(ldsA + seg * 1024), 16, 0, 0);
    }
    if (!diag) {
#pragma unroll
      for (int j = 0; j < 4; ++j) {
        int seg = wid * 4 + j;
        int row = seg * 8 + lrow;
        const unsigned short* src = xb + (size_t)(colBase + row) * d + g * 64
                                    + ((lp ^ (row & 7)) << 3);
        __builtin_amdgcn_global_load_lds(
            (const __attribute__((address_space(1))) void*)src,
            (__attribute__((address_space(3))) void*)(ldsB + seg * 1024), 16, 0, 0);
      }
    }
    __syncthreads();

#pragma unroll
    for (int kk = 0; kk < 2; ++kk) {
      bf16x8 a[4], b[4];
#pragma unroll
      for (int m = 0; m < 4; ++m) {
        int row = wr * 64 + m * 16 + l15;
        int slot = (kk * 4 + l4) ^ (row & 7);
        a[m] = *(const bf16x8*)(ldsA + row * 128 + slot * 16);
      }
#pragma unroll
      for (int nn = 0; nn < 4; ++nn) {
        int row = wc * 64 + nn * 16 + l15;
        int slot = (kk * 4 + l4) ^ (row & 7);
        b[nn] = *(const bf16x8*)(ldsBr + row * 128 + slot * 16);
      }
#pragma unroll
      for (int m = 0; m < 4; ++m)
#pragma unroll
        for (int nn = 0; nn < 4; ++nn)
          acc[m][nn] = __builtin_amdgcn_mfma_f32_16x16x32_bf16(a[m], b[nn], acc[m][nn], 0, 0, 0);
    }
  }

  // epilogue: C/D frag layout col=lane&15, row=(lane>>4)*4+r
  float cs[4] = {0.f, 0.f, 0.f, 0.f};
#pragma unroll
  for (int m = 0; m < 4; ++m) {
#pragma unroll
    for (int r = 0; r < 4; ++r) {
      int lr = wr * 64 + m * 16 + l4 * 4 + r;
      int gi = rowBase + lr;
      float ivr = ir_s[lr];
      int yi = yr_s[lr];
      float rs = 0.f;
#pragma unroll
      for (int nn = 0; nn < 4; ++nn) {
        int lc = wc * 64 + nn * 16 + l15;
        int gj = colBase + lc;
        float sim = acc[m][nn][r] * ivr * ic_s[lc];
        sim = fminf(fmaxf(sim, -1.0f + EPSf), 1.0f - EPSf);
        float s = fminf(__expf(sim * T_INV), 1e10f);
        if (yc_s[lc] != yi) {
          rs += s; cs[nn] += s;
        } else if (gi != gj) {
          S[(size_t)gi * MAXG + rc_s[lc]] = s;
          if (!diag) S[(size_t)gj * MAXG + rr_s[lr]] = s;
        }
      }
      rs += __shfl_xor(rs, 1, 64);
      rs += __shfl_xor(rs, 2, 64);
      rs += __shfl_xor(rs, 4, 64);
      rs += __shfl_xor(rs, 8, 64);
      if (l15 == 0) atomicAdd(&D[rowBase + lr], rs);
    }
  }
  if (!diag) {
#pragma unroll
    for (int nn = 0; nn < 4; ++nn) {
      float v = cs[nn];
      v += __shfl_xor(v, 16, 64);
      v += __shfl_xor(v, 32, 64);
      if (l4 == 0) atomicAdd(&D[colBase + wc * 64 + nn * 16 + l15], v);
    }
  }
}

// ---------------- Gram pass, fallback: reg-staged f32->bf16 ---------------
__global__ __launch_bounds__(256) void k_gram_reg(const float* __restrict__ x,
    const float* __restrict__ invn, const int* __restrict__ y,
    const int* __restrict__ rank, float* __restrict__ D, float* __restrict__ S,
    int n, int d, int nb) {
  int bid = blockIdx.x;
  int by = 0, rowlen = nb, rem = bid;
  while (rem >= rowlen) { rem -= rowlen; ++by; --rowlen; }
  int bx = by + rem;
  int rowBase = by * TS, colBase = bx * TS;
  bool diag = (bx == by);

  __shared__ char ldsA[128 * 128];
  __shared__ char ldsB[128 * 128];
  __shared__ float ir_s[128], ic_s[128];
  __shared__ int yr_s[128], yc_s[128];
  __shared__ int rr_s[128], rc_s[128];

  int t = threadIdx.x;
  int lane = t & 63, wid = t >> 6;
  int wr = wid >> 1, wc = wid & 1;
  int l15 = lane & 15, l4 = lane >> 4;

  if (t < 128) {
    ir_s[t] = invn[rowBase + t]; yr_s[t] = y[rowBase + t]; rr_s[t] = rank[rowBase + t];
    ic_s[t] = invn[colBase + t]; yc_s[t] = y[colBase + t]; rc_s[t] = rank[colBase + t];
  }

  f32x4 acc[4][4];
#pragma unroll
  for (int m = 0; m < 4; ++m)
#pragma unroll
    for (int nn = 0; nn < 4; ++nn) acc[m][nn] = (f32x4){0.f, 0.f, 0.f, 0.f};

  const char* ldsBr = diag ? ldsA : ldsB;

  for (int k0 = 0; k0 < d; k0 += 64) {
    __syncthreads();
#pragma unroll
    for (int i = 0; i < 8; ++i) {
      int c = t + i * 256;
      int row = c >> 4, fc = c & 15;
      float4 v = *(const float4*)(x + (size_t)(rowBase + row) * d + k0 + fc * 4);
      ushort4 h;
      h.x = f2bf(v.x); h.y = f2bf(v.y); h.z = f2bf(v.z); h.w = f2bf(v.w);
      int off = row * 128 + ((((fc >> 1) ^ (row & 7))) << 4) + (fc & 1) * 8;
      *(ushort4*)(ldsA + off) = h;
    }
    if (!diag) {
#pragma unroll
      for (int i = 0; i < 8; ++i) {
        int c = t + i * 256;
        int row = c >> 4, fc = c & 15;
        float4 v = *(const float4*)(x + (size_t)(colBase + row) * d + k0 + fc * 4);
        ushort4 h;
        h.x = f2bf(v.x); h.y = f2bf(v.y); h.z = f2bf(v.z); h.w = f2bf(v.w);
        int off = row * 128 + ((((fc >> 1) ^ (row & 7))) << 4) + (fc & 1) * 8;
        *(ushort4*)(ldsB + off) = h;
      }
    }
    __syncthreads();

#pragma unroll
    for (int kk = 0; kk < 2; ++kk) {
      bf16x8 a[4], b[4];
#pragma unroll
      for (int m = 0; m < 4; ++m) {
        int row = wr * 64 + m * 16 + l15;
        int slot = (kk * 4 + l4) ^ (row & 7);
        a[m] = *(const bf16x8*)(ldsA + row * 128 + slot * 16);
      }
#pragma unroll
      for (int nn = 0; nn < 4; ++nn) {
        int row = wc * 64 + nn * 16 + l15;
        int slot = (kk * 4 + l4) ^ (row & 7);
        b[nn] = *(const bf16x8*)(ldsBr + row * 128 + slot * 16);
      }
#pragma unroll
      for (int m = 0; m < 4; ++m)
#pragma unroll
        for (int nn = 0; nn < 4; ++nn)
          acc[m][nn] = __builtin_amdgcn_mfma_f32_16x16x32_bf16(a[m], b[nn], acc[m][nn], 0, 0, 0);
    }
  }

  float cs[4] = {0.f, 0.f, 0.f, 0.f};
#pragma unroll
  for (int m = 0; m < 4; ++m) {
#pragma unroll
    for (int r = 0; r < 4; ++r) {
      int lr = wr * 64 + m * 16 + l4 * 4 + r;
      int gi = rowBase + lr;
      float ivr = ir_s[lr];
      int yi = yr_s[lr];
      float rs = 0.f;
#pragma unroll
      for (int nn = 0; nn < 4; ++nn) {
        int lc = wc * 64 + nn * 16 + l15;
        int gj = colBase + lc;
        float sim = acc[m][nn][r] * ivr * ic_s[lc];
        sim = fminf(fmaxf(sim, -1.0f + EPSf), 1.0f - EPSf);
        float s = fminf(__expf(sim * T_INV), 1e10f);
        if (yc_s[lc] != yi) {
          rs += s; cs[nn] += s;
        } else if (S && gi != gj) {
          S[(size_t)gi * MAXG + rc_s[lc]] = s;
          if (!diag) S[(size_t)gj * MAXG + rr_s[lr]] = s;
        }
      }
      rs += __shfl_xor(rs, 1, 64);
      rs += __shfl_xor(rs, 2, 64);
      rs += __shfl_xor(rs, 4, 64);
      rs += __shfl_xor(rs, 8, 64);
      if (l15 == 0) atomicAdd(&D[rowBase + lr], rs);
    }
  }
  if (!diag) {
#pragma unroll
    for (int nn = 0; nn < 4; ++nn) {
      float v = cs[nn];
      v += __shfl_xor(v, 16, 64);
      v += __shfl_xor(v, 32, 64);
      if (l4 == 0) atomicAdd(&D[colBase + wc * 64 + nn * 16 + l15], v);
    }
  }
}

// Pass B (fast): read persisted same-label s values, sum the loss terms.
__global__ __launch_bounds__(256) void k_loss2(const int* __restrict__ y,
    const int* __restrict__ offs, const int* __restrict__ rows,
    const float* __restrict__ D, const float* __restrict__ S,
    float* __restrict__ accum, int n) {
  int gid = blockIdx.x * blockDim.x + threadIdx.x;
  int i = gid >> 7;          // MAXG = 128
  int slot = gid & (MAXG - 1);
  float term = 0.f;
  if (i < n) {
    int g = y[i];
    int start = offs[g], cnt = offs[g + 1] - start;
    if (slot < cnt) {
      int j = rows[start + slot];
      if (j != i) {
        float s = S[(size_t)i * MAXG + slot];
        term = logf(s + D[i] + EPSf) - logf(s);
      }
    }
  }
  term = wave_reduce_sum64(term);
  __shared__ float part[4];
  int lane = threadIdx.x & 63, wid = threadIdx.x >> 6;
  if (lane == 0) part[wid] = term;
  __syncthreads();
  if (threadIdx.x == 0) atomicAdd(accum, part[0] + part[1] + part[2] + part[3]);
}

// Pass B (fallback): recompute dots for same-label pairs
__global__ __launch_bounds__(256) void k_loss(const float* __restrict__ x,
    const float* __restrict__ invn, const int* __restrict__ y,
    const int* __restrict__ offs, const int* __restrict__ rows,
    const float* __restrict__ D, float* __restrict__ accum, int n, int d) {
  int i = blockIdx.x;
  int t = threadIdx.x, lane = t & 63, wid = t >> 6;
  __shared__ float4 xi4[256];
  __shared__ float wpart[4];

  const float4* xr = (const float4*)(x + (size_t)i * d);
  for (int q = t; q < d / 4; q += 256) xi4[q] = xr[q];
  __syncthreads();

  int g = y[i];
  int start = offs[g], end = offs[g + 1];
  float invi = invn[i];
  float Di = D[i];
  float wsum = 0.f;

  for (int idx = start + wid; idx < end; idx += 4) {
    int j = rows[idx];
    if (j == i) continue;
    const float4* xj = (const float4*)(x + (size_t)j * d);
    float acc = 0.f;
#pragma unroll 4
    for (int q = 0; q < d / 256; ++q) {
      float4 vj = xj[lane + 64 * q];
      float4 vi = xi4[lane + 64 * q];
      acc = fmaf(vj.x, vi.x, acc);
      acc = fmaf(vj.y, vi.y, acc);
      acc = fmaf(vj.z, vi.z, acc);
      acc = fmaf(vj.w, vi.w, acc);
    }
    acc = wave_reduce_sum64(acc);
    if (lane == 0) {
      float sim = acc * invi * invn[j];
      sim = fminf(fmaxf(sim, -1.0f + EPSf), 1.0f - EPSf);
      float s = fminf(expf(sim * T_INV), 1e10f);
      wsum += logf(s + Di + EPSf) - logf(s);
    }
  }

  if (lane == 0) wpart[wid] = wsum;
  __syncthreads();
  if (t == 0) atomicAdd(accum, wpart[0] + wpart[1] + wpart[2] + wpart[3]);
}

__global__ void k_final(const float* __restrict__ accum, float* __restrict__ out,
    int out_size, int n) {
  int i = blockIdx.x * blockDim.x + threadIdx.x;
  if (i < out_size) out[i] = *accum / (2.0f * n);
}

extern "C" void kernel_launch(void* const* d_in, const int* in_sizes, int n_in,
                              void* d_out, int out_size, void* d_ws, size_t ws_size,
                              hipStream_t stream) {
  const float* x = (const float*)d_in[0];
  const int*   y = (const int*)d_in[1];
  int n = in_sizes[1];
  int d = in_sizes[0] / n;

  char* ws = (char*)d_ws;
  float* invn  = (float*)(ws);            // 16 KB
  float* D     = (float*)(ws + 16384);    // 16 KB
  int*   offs  = (int*)(ws + 32768);      // 129 ints (pad to 2 KB)
  int*   rows  = (int*)(ws + 34816);      // 16 KB
  int*   rank  = (int*)(ws + 51200);      // 16 KB
  float* accum = (float*)(ws + 67584);    // 4 B (pad to 1 KB)
  float* S     = (float*)(ws + 68608);    // n*MAXG*4 = 2 MB
  size_t xb_off = 68608 + (size_t)n * MAXG * 4;
  xb_off = (xb_off + 255) & ~(size_t)255;
  unsigned short* xb = (unsigned short*)(ws + xb_off);

  bool hasS  = ws_size >= 68608 + (size_t)n * MAXG * 4;
  bool hasXb = hasS && ws_size >= xb_off + (size_t)n * d * 2;

  k_prep<<<n, 256, 0, stream>>>(x, invn, D, hasXb ? xb : nullptr, accum, n, d);
  k_labels<<<1, 256, 0, stream>>>(y, offs, rows, rank, n);

  int nb = n / TS;
  int nblocks = nb * (nb + 1) / 2;
  if (hasXb) {
    k_gram_ldsdma<<<nblocks, 256, 0, stream>>>(xb, invn, y, rank, D, S, n, d, nb);
  } else {
    k_gram_reg<<<nblocks, 256, 0, stream>>>(x, invn, y, rank, D, hasS ? S : nullptr, n, d, nb);
  }
  if (hasS) {
    k_loss2<<<(n * MAXG + 255) / 256, 256, 0, stream>>>(y, offs, rows, D, S, accum, n);
  } else {
    k_loss<<<n, 256, 0, stream>>>(x, invn, y, offs, rows, D, accum, n, d);
  }
  k_final<<<1, 64, 0, stream>>>(accum, (float*)d_out, out_size, n);
}